// Round 15
// baseline (1559.054 us; speedup 1.0000x reference)
//
#include <hip/hip_runtime.h>

// NeuralODE RK4, restructured algebra (W31 merged GEMM, hW1 state, XT deferred
// reconstruction) + MX-fp8 GEMM core. R15 = R14 with the fp8 GEMM at
// 4 blocks/CU: BK=64 (R8's proven staging), LDS shrunk to 35KB by overlaying
// the C-staging buffer onto the (dead-after-K-loop) staging buffers,
// __launch_bounds__(256,4). Doubled co-resident blocks hide the
// latency-type barrier-pair stalls (m114 wave-level overlap mechanism).

typedef __attribute__((ext_vector_type(8))) __bf16 bf16x8;
typedef __attribute__((ext_vector_type(4))) float f32x4;
typedef __attribute__((ext_vector_type(8))) float f32x8;
typedef __attribute__((ext_vector_type(16))) float f32x16;
typedef __attribute__((ext_vector_type(8))) unsigned short us8;
typedef __attribute__((ext_vector_type(4))) int i32x4;
typedef __attribute__((ext_vector_type(8))) int i32x8;
typedef unsigned short ushort_t;
typedef unsigned char u8;

#define SCALE_ONE  0x7F7F7F7Fu   // E8M0 1.0 per byte
#define SCALE_INV32 0x7A7A7A7Au  // E8M0 2^-5 per byte
#define HW1_SCALE 16.f
#define HW1_INV   0.0625f

#define GLOAD16(gp, lp) \
  __builtin_amdgcn_global_load_lds((const __attribute__((address_space(1))) unsigned int*)(gp), \
                                   (__attribute__((address_space(3))) unsigned int*)(lp), 16, 0, 0)

__device__ __forceinline__ ushort_t f2bf(float f) {
  union { float f; unsigned u; } v; v.f = f;
  unsigned r = v.u + 0x7fffu + ((v.u >> 16) & 1u);
  return (ushort_t)(r >> 16);
}
__device__ __forceinline__ float b2f(ushort_t u) {
  union { unsigned u; float f; } v; v.u = ((unsigned)u) << 16; return v.f;
}
__device__ __forceinline__ float fast_tanh(float x) {
  float e = __expf(2.0f * x);
  return 1.0f - 2.0f * __builtin_amdgcn_rcpf(e + 1.0f);
}
__device__ __forceinline__ uint2 pack_fp8x8(const float* v) {
  int a = __builtin_amdgcn_cvt_pk_fp8_f32(v[0], v[1], 0, false);
  a = __builtin_amdgcn_cvt_pk_fp8_f32(v[2], v[3], a, true);
  int b = __builtin_amdgcn_cvt_pk_fp8_f32(v[4], v[5], 0, false);
  b = __builtin_amdgcn_cvt_pk_fp8_f32(v[6], v[7], b, true);
  return make_uint2((unsigned)a, (unsigned)b);
}
__device__ __forceinline__ void fp8x4_to_f32(unsigned q, float* o) {
  o[0] = __builtin_amdgcn_cvt_f32_fp8(q, 0);
  o[1] = __builtin_amdgcn_cvt_f32_fp8(q, 1);
  o[2] = __builtin_amdgcn_cvt_f32_fp8(q, 2);
  o[3] = __builtin_amdgcn_cvt_f32_fp8(q, 3);
}
__device__ __forceinline__ void fp8x8_to_f32(uint2 q, float* o) {
  fp8x4_to_f32(q.x, o); fp8x4_to_f32(q.y, o + 4);
}

// ---------------- weight transpose (K x N fp32 -> N x K bf16) ----------------
__global__ void transpose_bf16(const float* __restrict__ in, ushort_t* __restrict__ out) {
  __shared__ float tile[32][33];
  const int bx = blockIdx.x * 32, by = blockIdx.y * 32;
  const int tx = threadIdx.x, ty = threadIdx.y;
#pragma unroll
  for (int i = 0; i < 32; i += 8)
    tile[ty + i][tx] = in[(size_t)(by + ty + i) * 1024 + bx + tx];
  __syncthreads();
#pragma unroll
  for (int i = 0; i < 32; i += 8)
    out[(size_t)(bx + ty + i) * 1024 + by + tx] = f2bf(tile[tx][ty + i]);
}

// ------------- weight transpose -> fp8 x32 (K x N fp32 -> N x K e4m3) -------
__global__ void transpose_fp8(const float* __restrict__ in, u8* __restrict__ out) {
  __shared__ float tile[32][33];
  const int bx = blockIdx.x * 32, by = blockIdx.y * 32;
  const int tx = threadIdx.x, ty = threadIdx.y;
#pragma unroll
  for (int i = 0; i < 32; i += 8)
    tile[ty + i][tx] = in[(size_t)(by + ty + i) * 1024 + bx + tx];
  __syncthreads();
#pragma unroll
  for (int i = 0; i < 32; i += 8) {
    const float v = 32.f * tile[tx][ty + i];
    int r = __builtin_amdgcn_cvt_pk_fp8_f32(v, v, 0, false);
    out[(size_t)(bx + ty + i) * 1024 + by + tx] = (u8)(r & 0xFF);
  }
}

// ---------------- fp32 -> bf16 convert ----------------
__global__ void conv_bf16(const float* __restrict__ in, ushort_t* __restrict__ out) {
  size_t i = ((size_t)blockIdx.x * 256 + threadIdx.x) * 4;
  float4 v = *(const float4*)&in[i];
  ushort4 o;
  o.x = f2bf(v.x); o.y = f2bf(v.y); o.z = f2bf(v.z); o.w = f2bf(v.w);
  *(ushort4*)&out[i] = o;
}

// ---------------- c31 = b3 @ W1a ----------------
__global__ void c31_kernel(const ushort_t* __restrict__ W1t, const float* __restrict__ b3,
                           float* __restrict__ c31) {
  const int j = blockIdx.x * 256 + threadIdx.x;
  float acc = 0.f;
  for (int c = 0; c < 128; ++c) {
    const us8 w = *(const us8*)&W1t[(size_t)j * 1024 + c * 8];
    const f32x8 b = *(const f32x8*)&b3[c * 8];
#pragma unroll
    for (int e = 0; e < 8; ++e) acc += b2f(w[e]) * b[e];
  }
  c31[j] = acc;
}

// ---------------- step-9 XT fold: XT += x2a + 2*x2b + 2*x2c + x2d ----------------
__global__ void xtfold(const u8* __restrict__ a, const u8* __restrict__ b,
                       const u8* __restrict__ c, const u8* __restrict__ d,
                       ushort_t* __restrict__ XT) {
  const size_t i = ((size_t)blockIdx.x * 256 + threadIdx.x) * 8;
  float va[8], vb[8], vc[8], vd[8];
  fp8x8_to_f32(*(const uint2*)&a[i], va);
  fp8x8_to_f32(*(const uint2*)&b[i], vb);
  fp8x8_to_f32(*(const uint2*)&c[i], vc);
  fp8x8_to_f32(*(const uint2*)&d[i], vd);
  const us8 xo = *(const us8*)&XT[i];
  us8 xn;
#pragma unroll
  for (int e = 0; e < 8; ++e)
    xn[e] = f2bf(b2f(xo[e]) + va[e] + 2.f * (vb[e] + vc[e]) + vd[e]);
  *(us8*)&XT[i] = xn;
}

// =================== bf16 GEMM (modes 0,1,5) — proven core ===================
// MODE 0: out8 = fp8(32*C)            (Bt31 precompute)
// MODE 1: out8b = fp8(16*C) [hW1]; out8 = fp8(tanh(C + bias)) [x1 @ t=0]
// MODE 5: outf = h0f + DT/6*C + bias  (final fp32 h)
template<int MODE>
__global__ void __launch_bounds__(256, 2)
gemm_bf16(const ushort_t* __restrict__ Ag, const ushort_t* __restrict__ Bg,
          const float* __restrict__ bias,
          u8* __restrict__ out8b, u8* __restrict__ out8,
          const float* __restrict__ h0f, float* __restrict__ outf)
{
  constexpr int K = 1024, NCOL = 1024, NT = 16;
  constexpr float DT = 0.1f;
  __shared__ __align__(16) ushort_t lds[2][16384];

  const int bid = blockIdx.x;
  const int nb = (int)gridDim.x >> 3;
  const int logical = (bid & 7) * nb + (bid >> 3);
  const int bm0 = (logical >> 3) * 128;
  const int bn0 = (logical & 7) * 128;

  const int tid = threadIdx.x;
  const int w = tid >> 6, l = tid & 63;
  const int wr = w >> 1, wc = w & 1;

  const int srow = l >> 3;
  const int sclog = (l & 7) ^ srow;
  const size_t gA0 = (size_t)(bm0 + w * 32 + srow) * K + sclog * 8;
  const size_t gB0 = (size_t)(bn0 + w * 32 + srow) * K + sclog * 8;
  const int ldsAo = w * 2048 + l * 8;
  const int ldsBo = 8192 + w * 2048 + l * 8;

#define STAGEB(s, t1) do { \
    const ushort_t* ga = Ag + gA0 + (size_t)(t1) * 64; \
    const ushort_t* gb = Bg + gB0 + (size_t)(t1) * 64; \
    GLOAD16(ga,          &lds[s][ldsAo]); \
    GLOAD16(ga + 8 * K,  &lds[s][ldsAo + 512]); \
    GLOAD16(ga + 16 * K, &lds[s][ldsAo + 1024]); \
    GLOAD16(ga + 24 * K, &lds[s][ldsAo + 1536]); \
    GLOAD16(gb,          &lds[s][ldsBo]); \
    GLOAD16(gb + 8 * K,  &lds[s][ldsBo + 512]); \
    GLOAD16(gb + 16 * K, &lds[s][ldsBo + 1024]); \
    GLOAD16(gb + 24 * K, &lds[s][ldsBo + 1536]); } while (0)

  const int r = l & 15, kb = l >> 4, xr = r & 7;
  const int aRow = (wr * 64 + r) * 64;
  const int bRow = 8192 + (wc * 64 + r) * 64;
  const int c0 = ((0 | kb) ^ xr) * 8;
  const int c1 = ((4 | kb) ^ xr) * 8;

  f32x4 acc[4][4];
#pragma unroll
  for (int m = 0; m < 4; ++m)
#pragma unroll
    for (int n = 0; n < 4; ++n) acc[m][n] = (f32x4){0.f, 0.f, 0.f, 0.f};

  STAGEB(0, 0);

  for (int t = 0; t < NT; ++t) {
    const int cur = t & 1;
    __builtin_amdgcn_s_barrier();
    if (t + 1 < NT) {
      STAGEB(cur ^ 1, t + 1);
      asm volatile("s_waitcnt vmcnt(8)" ::: "memory");
    } else {
      asm volatile("s_waitcnt vmcnt(0)" ::: "memory");
    }
    __builtin_amdgcn_s_barrier();
    __builtin_amdgcn_sched_barrier(0);

    const ushort_t* Lb = &lds[cur][0];
    bf16x8 av[4], bv[4];
#pragma unroll
    for (int m = 0; m < 4; ++m) av[m] = *(const bf16x8*)(Lb + aRow + m * 1024 + c0);
#pragma unroll
    for (int n = 0; n < 4; ++n) bv[n] = *(const bf16x8*)(Lb + bRow + n * 1024 + c0);
    __builtin_amdgcn_s_setprio(1);
#pragma unroll
    for (int m = 0; m < 4; ++m)
#pragma unroll
      for (int n = 0; n < 4; ++n)
        acc[m][n] = __builtin_amdgcn_mfma_f32_16x16x32_bf16(av[m], bv[n], acc[m][n], 0, 0, 0);
    __builtin_amdgcn_s_setprio(0);
#pragma unroll
    for (int m = 0; m < 4; ++m) av[m] = *(const bf16x8*)(Lb + aRow + m * 1024 + c1);
#pragma unroll
    for (int n = 0; n < 4; ++n) bv[n] = *(const bf16x8*)(Lb + bRow + n * 1024 + c1);
    __builtin_amdgcn_s_setprio(1);
#pragma unroll
    for (int m = 0; m < 4; ++m)
#pragma unroll
      for (int n = 0; n < 4; ++n)
        acc[m][n] = __builtin_amdgcn_mfma_f32_16x16x32_bf16(av[m], bv[n], acc[m][n], 0, 0, 0);
    __builtin_amdgcn_s_setprio(0);
  }
#undef STAGEB

  __syncthreads();
  ushort_t* C = &lds[0][0];
  const int er = (l >> 4) * 4;
  const int ec = l & 15;
#pragma unroll
  for (int n = 0; n < 4; ++n) {
    const int lc = wc * 64 + n * 16 + ec;
#pragma unroll
    for (int m = 0; m < 4; ++m) {
#pragma unroll
      for (int j = 0; j < 4; ++j) {
        const int lr = wr * 64 + m * 16 + er + j;
        C[lr * 136 + lc] = f2bf(acc[m][n][j]);
      }
    }
  }
  __syncthreads();

  constexpr float DT6 = DT / 6.f;
#pragma unroll
  for (int i = 0; i < 8; ++i) {
    const int chunk = tid + i * 256;
    const int row = chunk >> 4;
    const int cc = chunk & 15;
    const int col0 = bn0 + cc * 8;
    const us8 kv8 = *(const us8*)&C[row * 136 + cc * 8];
    const size_t gidx = (size_t)(bm0 + row) * NCOL + col0;

    if (MODE == 0) {
      float v[8];
#pragma unroll
      for (int e = 0; e < 8; ++e) v[e] = 32.f * b2f(kv8[e]);
      *(uint2*)&out8[gidx] = pack_fp8x8(v);
    } else if (MODE == 1) {
      const f32x8 b = *(const f32x8*)&bias[col0];
      float v[8], hv[8];
#pragma unroll
      for (int e = 0; e < 8; ++e) {
        const float c = b2f(kv8[e]);
        hv[e] = HW1_SCALE * c;
        v[e] = fast_tanh(c + b[e]);
      }
      *(uint2*)&out8b[gidx] = pack_fp8x8(hv);   // hW1 (fp8 x16)
      *(uint2*)&out8[gidx]  = pack_fp8x8(v);    // x1 (fp8)
    } else {  // MODE 5
      const f32x8 b = *(const f32x8*)&bias[col0];
      const f32x8 h8 = *(const f32x8*)&h0f[gidx];
      f32x8 o;
#pragma unroll
      for (int e = 0; e < 8; ++e) o[e] = h8[e] + DT6 * b2f(kv8[e]) + b[e];
      *(f32x8*)&outf[gidx] = o;
    }
  }
}

// =================== MX-fp8 GEMM (modes 2,3,4), BK=64, 4 blocks/CU ===================
// C[i][j] = sum_k A[i][k]*Bt[j][k]*2^-5 via mfma_scale (B stored x32).
// LDS = 35KB (2x16KB staging, Cst 34KB overlay) -> 4 blocks/CU.
// MODE 2: out8 = fp8(tanh(C + bias))                      (x2 stage buffer)
// MODE 3: g = C; gout = fp8(g);
//         out8 = fp8(tanh(hW1/16 + p1*(g + c31) + b + p2*wl))
// MODE 4: hn = hW1/16 + DT/6*(g0+2g1+2g2+C) + DT*c31; hW1w = fp8(16*hn);
//         out8 = fp8(tanh(hn + b + p2*wl)); XT (+)= x2a+2x2b+2x2c+Ag
template<int MODE>
__global__ void __launch_bounds__(256, 4)
gemm_fp8(const u8* __restrict__ Ag, const u8* __restrict__ Bg,
         const float* __restrict__ bias, const float* __restrict__ wl,
         const float* __restrict__ c31,
         const u8* __restrict__ hW1r,
         const u8* __restrict__ g0p, const u8* __restrict__ g1p, const u8* __restrict__ g2p,
         const u8* __restrict__ x2a, const u8* __restrict__ x2b, const u8* __restrict__ x2c,
         u8* __restrict__ out8, u8* __restrict__ gout,
         ushort_t* __restrict__ bfio, u8* __restrict__ hW1w,
         float p1, float p2, int flag)
{
  constexpr int NT = 16;  // BK = 64 fp8 bytes
  constexpr float DT = 0.1f, DT6 = DT / 6.f;
  // staging: 2 x (A 8KB | B 8KB) = 32KB; Cst (34816B) overlays -> 35840B total
  __shared__ __align__(16) u8 ldsraw[35840];

  const int bid = blockIdx.x;
  const int nb = (int)gridDim.x >> 3;
  const int logical = (bid & 7) * nb + (bid >> 3);
  const int bm0 = (logical >> 3) * 128;
  const int bn0 = (logical & 7) * 128;

  const int tid = threadIdx.x;
  const int w = tid >> 6, l = tid & 63;
  const int wr = w >> 1, wc = w & 1;
  const int l31 = l & 31, kg = l >> 5;

  // ---- staging (R8-proven): slot s holds 16B; source pre-swizzled ----
  auto srcoff = [](int slot) -> int {
    int rp = slot >> 3, p = slot & 7, q = p ^ (rp & 7);
    return (2 * rp + (q >> 2)) * 1024 + (q & 3) * 16;
  };
  const int so0 = srcoff(tid), so1 = srcoff(256 + tid);
  const u8* gA = Ag + (size_t)bm0 * 1024;
  const u8* gB = Bg + (size_t)bn0 * 1024;
  const int ld0 = tid * 16, ld1 = 4096 + tid * 16;

#define STAGEF(s, t1) do { \
    u8* base = ldsraw + (s) * 16384; \
    GLOAD16(gA + so0 + (t1) * 64, base + ld0); \
    GLOAD16(gA + so1 + (t1) * 64, base + ld1); \
    GLOAD16(gB + so0 + (t1) * 64, base + 8192 + ld0); \
    GLOAD16(gB + so1 + (t1) * 64, base + 8192 + ld1); } while (0)

  // ---- fragment addresses (R8-proven): lane reads 32B (k = kg*32..+32) ----
  auto ldsAddr = [](int r2, int kc) -> int {
    int q = ((r2 & 1) << 2) | kc; int p = q ^ ((r2 >> 1) & 7);
    return (r2 >> 1) * 128 + p * 16;
  };
  const int kc2 = kg * 2;
  const int ra0 = wr * 64 + l31, ra1 = ra0 + 32;
  const int rb0 = wc * 64 + l31, rb1 = rb0 + 32;
  const int aA00 = ldsAddr(ra0, kc2), aA01 = ldsAddr(ra0, kc2 + 1);
  const int aA10 = ldsAddr(ra1, kc2), aA11 = ldsAddr(ra1, kc2 + 1);
  const int bA00 = 8192 + ldsAddr(rb0, kc2), bA01 = 8192 + ldsAddr(rb0, kc2 + 1);
  const int bA10 = 8192 + ldsAddr(rb1, kc2), bA11 = 8192 + ldsAddr(rb1, kc2 + 1);

  f32x16 acc00, acc01, acc10, acc11;
#pragma unroll
  for (int i = 0; i < 16; ++i) { acc00[i] = 0.f; acc01[i] = 0.f; acc10[i] = 0.f; acc11[i] = 0.f; }

#define LD8(dst, o0, o1) do { \
    i32x4 lo_ = *(const i32x4*)(Lb + (o0)); \
    i32x4 hi_ = *(const i32x4*)(Lb + (o1)); \
    dst = (i32x8){lo_[0], lo_[1], lo_[2], lo_[3], hi_[0], hi_[1], hi_[2], hi_[3]}; } while (0)

  STAGEF(0, 0);

  for (int t = 0; t < NT; ++t) {
    const int cur = t & 1;
    __builtin_amdgcn_s_barrier();
    if (t + 1 < NT) {
      STAGEF(cur ^ 1, t + 1);
      asm volatile("s_waitcnt vmcnt(4)" ::: "memory");
    } else {
      asm volatile("s_waitcnt vmcnt(0)" ::: "memory");
    }
    __builtin_amdgcn_s_barrier();
    __builtin_amdgcn_sched_barrier(0);

    const u8* Lb = ldsraw + cur * 16384;
    i32x8 a0, a1, b0, b1;
    LD8(a0, aA00, aA01);
    LD8(a1, aA10, aA11);
    LD8(b0, bA00, bA01);
    LD8(b1, bA10, bA11);
    __builtin_amdgcn_s_setprio(1);
    acc00 = __builtin_amdgcn_mfma_scale_f32_32x32x64_f8f6f4(a0, b0, acc00, 0, 0, 0, SCALE_ONE, 0, SCALE_INV32);
    acc01 = __builtin_amdgcn_mfma_scale_f32_32x32x64_f8f6f4(a0, b1, acc01, 0, 0, 0, SCALE_ONE, 0, SCALE_INV32);
    acc10 = __builtin_amdgcn_mfma_scale_f32_32x32x64_f8f6f4(a1, b0, acc10, 0, 0, 0, SCALE_ONE, 0, SCALE_INV32);
    acc11 = __builtin_amdgcn_mfma_scale_f32_32x32x64_f8f6f4(a1, b1, acc11, 0, 0, 0, SCALE_ONE, 0, SCALE_INV32);
    __builtin_amdgcn_s_setprio(0);
  }
#undef STAGEF

  // ---- stage raw bf16(C) to LDS (overlay on staging; barrier first);
  //      32x32 C/D layout: col = lane&31, row = (reg&3)+8*(reg>>2)+4*(lane>>5)
  __syncthreads();
  ushort_t* Cst = (ushort_t*)&ldsraw[0];      // 128 x 136 bf16 = 34816B <= 35840B
#define STORE_ACC(A_, mm, nn) do { \
    _Pragma("unroll") \
    for (int reg = 0; reg < 16; ++reg) { \
      const int lrow = wr * 64 + (mm) * 32 + (reg & 3) + 8 * (reg >> 2) + 4 * kg; \
      const int lcol = wc * 64 + (nn) * 32 + l31; \
      Cst[lrow * 136 + lcol] = f2bf(A_[reg]); } } while (0)
  STORE_ACC(acc00, 0, 0);
  STORE_ACC(acc01, 0, 1);
  STORE_ACC(acc10, 1, 0);
  STORE_ACC(acc11, 1, 1);
#undef STORE_ACC

  // ---- state pre-reads (accs dead -> VGPR headroom); overlap LDS-write drain ----
  uint2 hw_pre[8];
  if (MODE == 3 || MODE == 4) {
#pragma unroll
    for (int i = 0; i < 8; ++i) {
      const int chunk = tid + i * 256;
      const size_t gidx = (size_t)(bm0 + (chunk >> 4)) * 1024 + bn0 + (chunk & 15) * 8;
      hw_pre[i] = *(const uint2*)&hW1r[gidx];
    }
  }
  uint2 g0_pre[8], g1_pre[8], g2_pre[8];
  if (MODE == 4) {
#pragma unroll
    for (int i = 0; i < 8; ++i) {
      const int chunk = tid + i * 256;
      const size_t gidx = (size_t)(bm0 + (chunk >> 4)) * 1024 + bn0 + (chunk & 15) * 8;
      g0_pre[i] = *(const uint2*)&g0p[gidx];
      g1_pre[i] = *(const uint2*)&g1p[gidx];
      g2_pre[i] = *(const uint2*)&g2p[gidx];
    }
  }
  __syncthreads();

#pragma unroll
  for (int i = 0; i < 8; ++i) {
    const int chunk = tid + i * 256;
    const int row = chunk >> 4;
    const int cc = chunk & 15;
    const int col0 = bn0 + cc * 8;
    const us8 kv8 = *(const us8*)&Cst[row * 136 + cc * 8];
    const size_t gidx = (size_t)(bm0 + row) * 1024 + col0;

    if (MODE == 2) {
      const f32x8 b = *(const f32x8*)&bias[col0];
      float x2v[8];
#pragma unroll
      for (int e = 0; e < 8; ++e) x2v[e] = fast_tanh(b2f(kv8[e]) + b[e]);
      *(uint2*)&out8[gidx] = pack_fp8x8(x2v);
    } else if (MODE == 3) {
      const f32x8 b  = *(const f32x8*)&bias[col0];
      const f32x8 wv = *(const f32x8*)&wl[col0];
      const f32x8 cv = *(const f32x8*)&c31[col0];
      float hwv[8];
      fp8x8_to_f32(hw_pre[i], hwv);
      float gv[8], x1v[8];
#pragma unroll
      for (int e = 0; e < 8; ++e) {
        gv[e] = b2f(kv8[e]);
        x1v[e] = fast_tanh(hwv[e] * HW1_INV + p1 * (gv[e] + cv[e]) + b[e] + p2 * wv[e]);
      }
      *(uint2*)&gout[gidx] = pack_fp8x8(gv);
      *(uint2*)&out8[gidx] = pack_fp8x8(x1v);
    } else {  // MODE 4
      const f32x8 b  = *(const f32x8*)&bias[col0];
      const f32x8 wv = *(const f32x8*)&wl[col0];
      const f32x8 cv = *(const f32x8*)&c31[col0];
      float hwv[8];
      fp8x8_to_f32(hw_pre[i], hwv);
      float g0v[8], g1v[8], g2v[8];
      fp8x8_to_f32(g0_pre[i], g0v);
      fp8x8_to_f32(g1_pre[i], g1v);
      fp8x8_to_f32(g2_pre[i], g2v);
      // XT fold: x2a + 2*x2b + 2*x2c + x2d(=Ag)
      float va[8], vb[8], vc[8], vd[8];
      fp8x8_to_f32(*(const uint2*)&x2a[gidx], va);
      fp8x8_to_f32(*(const uint2*)&x2b[gidx], vb);
      fp8x8_to_f32(*(const uint2*)&x2c[gidx], vc);
      fp8x8_to_f32(*(const uint2*)&Ag[gidx], vd);
      us8 xtn;
      if (flag) {
#pragma unroll
        for (int e = 0; e < 8; ++e)
          xtn[e] = f2bf(va[e] + 2.f * (vb[e] + vc[e]) + vd[e]);
      } else {
        const us8 xo = *(const us8*)&bfio[gidx];
#pragma unroll
        for (int e = 0; e < 8; ++e)
          xtn[e] = f2bf(b2f(xo[e]) + va[e] + 2.f * (vb[e] + vc[e]) + vd[e]);
      }
      *(us8*)&bfio[gidx] = xtn;
      // h-state update: hW1 += DT/6*(g0 + 2g1 + 2g2 + g4) + DT*c31
      float x1v[8], hn16[8];
#pragma unroll
      for (int e = 0; e < 8; ++e) {
        const float gs = g0v[e] + 2.f * (g1v[e] + g2v[e]) + b2f(kv8[e]);
        const float hn = hwv[e] * HW1_INV + DT6 * gs + DT * cv[e];
        hn16[e] = HW1_SCALE * hn;
        x1v[e] = fast_tanh(hn + b[e] + p2 * wv[e]);
      }
      *(uint2*)&hW1w[gidx] = pack_fp8x8(hn16);
      *(uint2*)&out8[gidx] = pack_fp8x8(x1v);
    }
  }
}

extern "C" void kernel_launch(void* const* d_in, const int* in_sizes, int n_in,
                              void* d_out, int out_size, void* d_ws, size_t ws_size,
                              hipStream_t stream) {
  (void)in_sizes; (void)n_in; (void)out_size; (void)ws_size;
  const float* h_in = (const float*)d_in[0];
  const float* W1   = (const float*)d_in[1];   // 1025 x 1024
  const float* b1   = (const float*)d_in[2];
  const float* W2   = (const float*)d_in[3];
  const float* b2   = (const float*)d_in[4];
  const float* W3   = (const float*)d_in[5];
  const float* b3   = (const float*)d_in[6];
  const float* W1last = W1 + (size_t)1024 * 1024;

  char* ws = (char*)d_ws;
  ushort_t* W1t   = (ushort_t*)(ws);                   // 2 MiB (reused for W3^T at end)
  u8*       W2t8  = (u8*)      (ws + (2ull << 20));    // 1 MiB fp8 x32
  u8*       Bt318 = (u8*)      (ws + (3ull << 20));    // 1 MiB fp8 x32
  float*    c31   = (float*)   (ws + (4ull << 20));    // 4 KiB
  u8*       hW18  = (u8*)      (ws + (8ull << 20));    // 8 MiB fp8 x16 hW1
  u8*       x1    = (u8*)      (ws + (24ull << 20));   // 8 MiB fp8
  u8*       x2s0  = (u8*)      (ws + (32ull << 20));   // 8 MiB fp8
  u8*       x2s1  = (u8*)      (ws + (40ull << 20));   // 8 MiB fp8
  u8*       x2s2  = (u8*)      (ws + (48ull << 20));   // 8 MiB fp8
  u8*       x2s3  = (u8*)      (ws + (56ull << 20));   // 8 MiB fp8
  ushort_t* XT    = (ushort_t*)(ws + (64ull << 20));   // 16 MiB bf16 (W3b transient)
  u8*       g0    = (u8*)d_out;                        // 8 MiB fp8 (d_out, dead until final)
  u8*       g1    = (u8*)d_out + (8ull << 20);         // 8 MiB fp8
  u8*       g2    = (u8*)d_out + (16ull << 20);        // 8 MiB fp8
  ushort_t* hb    = (ushort_t*)d_out;                  // bf16 h (dead after MODE1)
  float*    OUT   = (float*)d_out;

  const float dt = 0.1f;
  constexpr int GRID = 512, BLK = 256;
  dim3 tb(32, 8), tg(32, 32);

  // ---- precompute ----
  transpose_bf16<<<tg, tb, 0, stream>>>(W1, W1t);
  transpose_fp8 <<<tg, tb, 0, stream>>>(W2, W2t8);
  conv_bf16<<<1024, 256, 0, stream>>>(W3, XT);         // W3b transient in XT slot
  conv_bf16<<<8192, 256, 0, stream>>>(h_in, hb);
  c31_kernel<<<4, 256, 0, stream>>>(W1t, b3, c31);
  gemm_bf16<0><<<64, BLK, 0, stream>>>(W1t, XT, nullptr, nullptr, Bt318, nullptr, nullptr);
  gemm_bf16<1><<<GRID, BLK, 0, stream>>>(hb, W1t, b1, hW18, x1, nullptr, nullptr);

  for (int step = 0; step < 10; ++step) {
    const float t0 = step * dt;
    // stage 1
    gemm_fp8<2><<<GRID, BLK, 0, stream>>>(x1, W2t8, b2, nullptr, nullptr, nullptr,
                                          nullptr, nullptr, nullptr, nullptr, nullptr, nullptr,
                                          x2s0, nullptr, nullptr, nullptr, 0.f, 0.f, 0);
    gemm_fp8<3><<<GRID, BLK, 0, stream>>>(x2s0, Bt318, b1, W1last, c31, hW18,
                                          nullptr, nullptr, nullptr, nullptr, nullptr, nullptr,
                                          x1, g0, nullptr, nullptr, 0.5f * dt, t0 + 0.5f * dt, 0);
    // stage 2
    gemm_fp8<2><<<GRID, BLK, 0, stream>>>(x1, W2t8, b2, nullptr, nullptr, nullptr,
                                          nullptr, nullptr, nullptr, nullptr, nullptr, nullptr,
                                          x2s1, nullptr, nullptr, nullptr, 0.f, 0.f, 0);
    gemm_fp8<3><<<GRID, BLK, 0, stream>>>(x2s1, Bt318, b1, W1last, c31, hW18,
                                          nullptr, nullptr, nullptr, nullptr, nullptr, nullptr,
                                          x1, g1, nullptr, nullptr, 0.5f * dt, t0 + 0.5f * dt, 0);
    // stage 3
    gemm_fp8<2><<<GRID, BLK, 0, stream>>>(x1, W2t8, b2, nullptr, nullptr, nullptr,
                                          nullptr, nullptr, nullptr, nullptr, nullptr, nullptr,
                                          x2s2, nullptr, nullptr, nullptr, 0.f, 0.f, 0);
    gemm_fp8<3><<<GRID, BLK, 0, stream>>>(x2s2, Bt318, b1, W1last, c31, hW18,
                                          nullptr, nullptr, nullptr, nullptr, nullptr, nullptr,
                                          x1, g2, nullptr, nullptr, dt, t0 + dt, 0);
    // stage 4
    gemm_fp8<2><<<GRID, BLK, 0, stream>>>(x1, W2t8, b2, nullptr, nullptr, nullptr,
                                          nullptr, nullptr, nullptr, nullptr, nullptr, nullptr,
                                          x2s3, nullptr, nullptr, nullptr, 0.f, 0.f, 0);
    if (step < 9) {
      gemm_fp8<4><<<GRID, BLK, 0, stream>>>(x2s3, Bt318, b1, W1last, c31, hW18,
                                            g0, g1, g2, x2s0, x2s1, x2s2,
                                            x1, nullptr, XT, hW18,
                                            0.f, t0 + dt, (step == 0));
    }
  }
  // step-9 XT contribution (no MODE4 needed — hW1 no longer used)
  xtfold<<<4096, 256, 0, stream>>>(x2s0, x2s1, x2s2, x2s3, XT);

  // final: h = h0 + dt/6 * XT@W3 + b3
  transpose_bf16<<<tg, tb, 0, stream>>>(W3, W1t);
  gemm_bf16<5><<<GRID, BLK, 0, stream>>>(XT, W1t, b3, nullptr, nullptr, h_in, OUT);
}

// Round 16
// 1423.806 us; speedup vs baseline: 1.0950x; 1.0950x over previous
//
#include <hip/hip_runtime.h>

// NeuralODE RK4, restructured algebra (W31 merged GEMM, hW1 state, XT deferred
// reconstruction) + MX-fp8 GEMM core, BK=128, 2 blocks/CU (R14 exact revert —
// best verified config, 1429us). R15's 4-blocks/CU failed: launch_bounds cap
// forced VGPR=64 < 64-reg accumulator -> scratch spills (41us dispatches).

typedef __attribute__((ext_vector_type(8))) __bf16 bf16x8;
typedef __attribute__((ext_vector_type(4))) float f32x4;
typedef __attribute__((ext_vector_type(8))) float f32x8;
typedef __attribute__((ext_vector_type(16))) float f32x16;
typedef __attribute__((ext_vector_type(8))) unsigned short us8;
typedef __attribute__((ext_vector_type(4))) int i32x4;
typedef __attribute__((ext_vector_type(8))) int i32x8;
typedef unsigned short ushort_t;
typedef unsigned char u8;

#define SCALE_ONE  0x7F7F7F7Fu   // E8M0 1.0 per byte
#define SCALE_INV32 0x7A7A7A7Au  // E8M0 2^-5 per byte
#define HW1_SCALE 16.f
#define HW1_INV   0.0625f

#define GLOAD16(gp, lp) \
  __builtin_amdgcn_global_load_lds((const __attribute__((address_space(1))) unsigned int*)(gp), \
                                   (__attribute__((address_space(3))) unsigned int*)(lp), 16, 0, 0)

__device__ __forceinline__ ushort_t f2bf(float f) {
  union { float f; unsigned u; } v; v.f = f;
  unsigned r = v.u + 0x7fffu + ((v.u >> 16) & 1u);
  return (ushort_t)(r >> 16);
}
__device__ __forceinline__ float b2f(ushort_t u) {
  union { unsigned u; float f; } v; v.u = ((unsigned)u) << 16; return v.f;
}
__device__ __forceinline__ float fast_tanh(float x) {
  float e = __expf(2.0f * x);
  return 1.0f - 2.0f * __builtin_amdgcn_rcpf(e + 1.0f);
}
__device__ __forceinline__ uint2 pack_fp8x8(const float* v) {
  int a = __builtin_amdgcn_cvt_pk_fp8_f32(v[0], v[1], 0, false);
  a = __builtin_amdgcn_cvt_pk_fp8_f32(v[2], v[3], a, true);
  int b = __builtin_amdgcn_cvt_pk_fp8_f32(v[4], v[5], 0, false);
  b = __builtin_amdgcn_cvt_pk_fp8_f32(v[6], v[7], b, true);
  return make_uint2((unsigned)a, (unsigned)b);
}
__device__ __forceinline__ void fp8x4_to_f32(unsigned q, float* o) {
  o[0] = __builtin_amdgcn_cvt_f32_fp8(q, 0);
  o[1] = __builtin_amdgcn_cvt_f32_fp8(q, 1);
  o[2] = __builtin_amdgcn_cvt_f32_fp8(q, 2);
  o[3] = __builtin_amdgcn_cvt_f32_fp8(q, 3);
}
__device__ __forceinline__ void fp8x8_to_f32(uint2 q, float* o) {
  fp8x4_to_f32(q.x, o); fp8x4_to_f32(q.y, o + 4);
}

// ---------------- weight transpose (K x N fp32 -> N x K bf16) ----------------
__global__ void transpose_bf16(const float* __restrict__ in, ushort_t* __restrict__ out) {
  __shared__ float tile[32][33];
  const int bx = blockIdx.x * 32, by = blockIdx.y * 32;
  const int tx = threadIdx.x, ty = threadIdx.y;
#pragma unroll
  for (int i = 0; i < 32; i += 8)
    tile[ty + i][tx] = in[(size_t)(by + ty + i) * 1024 + bx + tx];
  __syncthreads();
#pragma unroll
  for (int i = 0; i < 32; i += 8)
    out[(size_t)(bx + ty + i) * 1024 + by + tx] = f2bf(tile[tx][ty + i]);
}

// ------------- weight transpose -> fp8 x32 (K x N fp32 -> N x K e4m3) -------
__global__ void transpose_fp8(const float* __restrict__ in, u8* __restrict__ out) {
  __shared__ float tile[32][33];
  const int bx = blockIdx.x * 32, by = blockIdx.y * 32;
  const int tx = threadIdx.x, ty = threadIdx.y;
#pragma unroll
  for (int i = 0; i < 32; i += 8)
    tile[ty + i][tx] = in[(size_t)(by + ty + i) * 1024 + bx + tx];
  __syncthreads();
#pragma unroll
  for (int i = 0; i < 32; i += 8) {
    const float v = 32.f * tile[tx][ty + i];
    int r = __builtin_amdgcn_cvt_pk_fp8_f32(v, v, 0, false);
    out[(size_t)(bx + ty + i) * 1024 + by + tx] = (u8)(r & 0xFF);
  }
}

// ---------------- fp32 -> bf16 convert ----------------
__global__ void conv_bf16(const float* __restrict__ in, ushort_t* __restrict__ out) {
  size_t i = ((size_t)blockIdx.x * 256 + threadIdx.x) * 4;
  float4 v = *(const float4*)&in[i];
  ushort4 o;
  o.x = f2bf(v.x); o.y = f2bf(v.y); o.z = f2bf(v.z); o.w = f2bf(v.w);
  *(ushort4*)&out[i] = o;
}

// ---------------- c31 = b3 @ W1a ----------------
__global__ void c31_kernel(const ushort_t* __restrict__ W1t, const float* __restrict__ b3,
                           float* __restrict__ c31) {
  const int j = blockIdx.x * 256 + threadIdx.x;
  float acc = 0.f;
  for (int c = 0; c < 128; ++c) {
    const us8 w = *(const us8*)&W1t[(size_t)j * 1024 + c * 8];
    const f32x8 b = *(const f32x8*)&b3[c * 8];
#pragma unroll
    for (int e = 0; e < 8; ++e) acc += b2f(w[e]) * b[e];
  }
  c31[j] = acc;
}

// ---------------- step-9 XT fold: XT += x2a + 2*x2b + 2*x2c + x2d ----------------
__global__ void xtfold(const u8* __restrict__ a, const u8* __restrict__ b,
                       const u8* __restrict__ c, const u8* __restrict__ d,
                       ushort_t* __restrict__ XT) {
  const size_t i = ((size_t)blockIdx.x * 256 + threadIdx.x) * 8;
  float va[8], vb[8], vc[8], vd[8];
  fp8x8_to_f32(*(const uint2*)&a[i], va);
  fp8x8_to_f32(*(const uint2*)&b[i], vb);
  fp8x8_to_f32(*(const uint2*)&c[i], vc);
  fp8x8_to_f32(*(const uint2*)&d[i], vd);
  const us8 xo = *(const us8*)&XT[i];
  us8 xn;
#pragma unroll
  for (int e = 0; e < 8; ++e)
    xn[e] = f2bf(b2f(xo[e]) + va[e] + 2.f * (vb[e] + vc[e]) + vd[e]);
  *(us8*)&XT[i] = xn;
}

// =================== bf16 GEMM (modes 0,1,5) — proven core ===================
// MODE 0: out8 = fp8(32*C)            (Bt31 precompute)
// MODE 1: out8b = fp8(16*C) [hW1]; out8 = fp8(tanh(C + bias)) [x1 @ t=0]
// MODE 5: outf = h0f + DT/6*C + bias  (final fp32 h)
template<int MODE>
__global__ void __launch_bounds__(256, 2)
gemm_bf16(const ushort_t* __restrict__ Ag, const ushort_t* __restrict__ Bg,
          const float* __restrict__ bias,
          u8* __restrict__ out8b, u8* __restrict__ out8,
          const float* __restrict__ h0f, float* __restrict__ outf)
{
  constexpr int K = 1024, NCOL = 1024, NT = 16;
  constexpr float DT = 0.1f;
  __shared__ __align__(16) ushort_t lds[2][16384];

  const int bid = blockIdx.x;
  const int nb = (int)gridDim.x >> 3;
  const int logical = (bid & 7) * nb + (bid >> 3);
  const int bm0 = (logical >> 3) * 128;
  const int bn0 = (logical & 7) * 128;

  const int tid = threadIdx.x;
  const int w = tid >> 6, l = tid & 63;
  const int wr = w >> 1, wc = w & 1;

  const int srow = l >> 3;
  const int sclog = (l & 7) ^ srow;
  const size_t gA0 = (size_t)(bm0 + w * 32 + srow) * K + sclog * 8;
  const size_t gB0 = (size_t)(bn0 + w * 32 + srow) * K + sclog * 8;
  const int ldsAo = w * 2048 + l * 8;
  const int ldsBo = 8192 + w * 2048 + l * 8;

#define STAGEB(s, t1) do { \
    const ushort_t* ga = Ag + gA0 + (size_t)(t1) * 64; \
    const ushort_t* gb = Bg + gB0 + (size_t)(t1) * 64; \
    GLOAD16(ga,          &lds[s][ldsAo]); \
    GLOAD16(ga + 8 * K,  &lds[s][ldsAo + 512]); \
    GLOAD16(ga + 16 * K, &lds[s][ldsAo + 1024]); \
    GLOAD16(ga + 24 * K, &lds[s][ldsAo + 1536]); \
    GLOAD16(gb,          &lds[s][ldsBo]); \
    GLOAD16(gb + 8 * K,  &lds[s][ldsBo + 512]); \
    GLOAD16(gb + 16 * K, &lds[s][ldsBo + 1024]); \
    GLOAD16(gb + 24 * K, &lds[s][ldsBo + 1536]); } while (0)

  const int r = l & 15, kb = l >> 4, xr = r & 7;
  const int aRow = (wr * 64 + r) * 64;
  const int bRow = 8192 + (wc * 64 + r) * 64;
  const int c0 = ((0 | kb) ^ xr) * 8;
  const int c1 = ((4 | kb) ^ xr) * 8;

  f32x4 acc[4][4];
#pragma unroll
  for (int m = 0; m < 4; ++m)
#pragma unroll
    for (int n = 0; n < 4; ++n) acc[m][n] = (f32x4){0.f, 0.f, 0.f, 0.f};

  STAGEB(0, 0);

  for (int t = 0; t < NT; ++t) {
    const int cur = t & 1;
    __builtin_amdgcn_s_barrier();
    if (t + 1 < NT) {
      STAGEB(cur ^ 1, t + 1);
      asm volatile("s_waitcnt vmcnt(8)" ::: "memory");
    } else {
      asm volatile("s_waitcnt vmcnt(0)" ::: "memory");
    }
    __builtin_amdgcn_s_barrier();
    __builtin_amdgcn_sched_barrier(0);

    const ushort_t* Lb = &lds[cur][0];
    bf16x8 av[4], bv[4];
#pragma unroll
    for (int m = 0; m < 4; ++m) av[m] = *(const bf16x8*)(Lb + aRow + m * 1024 + c0);
#pragma unroll
    for (int n = 0; n < 4; ++n) bv[n] = *(const bf16x8*)(Lb + bRow + n * 1024 + c0);
    __builtin_amdgcn_s_setprio(1);
#pragma unroll
    for (int m = 0; m < 4; ++m)
#pragma unroll
      for (int n = 0; n < 4; ++n)
        acc[m][n] = __builtin_amdgcn_mfma_f32_16x16x32_bf16(av[m], bv[n], acc[m][n], 0, 0, 0);
    __builtin_amdgcn_s_setprio(0);
#pragma unroll
    for (int m = 0; m < 4; ++m) av[m] = *(const bf16x8*)(Lb + aRow + m * 1024 + c1);
#pragma unroll
    for (int n = 0; n < 4; ++n) bv[n] = *(const bf16x8*)(Lb + bRow + n * 1024 + c1);
    __builtin_amdgcn_s_setprio(1);
#pragma unroll
    for (int m = 0; m < 4; ++m)
#pragma unroll
      for (int n = 0; n < 4; ++n)
        acc[m][n] = __builtin_amdgcn_mfma_f32_16x16x32_bf16(av[m], bv[n], acc[m][n], 0, 0, 0);
    __builtin_amdgcn_s_setprio(0);
  }
#undef STAGEB

  __syncthreads();
  ushort_t* C = &lds[0][0];
  const int er = (l >> 4) * 4;
  const int ec = l & 15;
#pragma unroll
  for (int n = 0; n < 4; ++n) {
    const int lc = wc * 64 + n * 16 + ec;
#pragma unroll
    for (int m = 0; m < 4; ++m) {
#pragma unroll
      for (int j = 0; j < 4; ++j) {
        const int lr = wr * 64 + m * 16 + er + j;
        C[lr * 136 + lc] = f2bf(acc[m][n][j]);
      }
    }
  }
  __syncthreads();

  constexpr float DT6 = DT / 6.f;
#pragma unroll
  for (int i = 0; i < 8; ++i) {
    const int chunk = tid + i * 256;
    const int row = chunk >> 4;
    const int cc = chunk & 15;
    const int col0 = bn0 + cc * 8;
    const us8 kv8 = *(const us8*)&C[row * 136 + cc * 8];
    const size_t gidx = (size_t)(bm0 + row) * NCOL + col0;

    if (MODE == 0) {
      float v[8];
#pragma unroll
      for (int e = 0; e < 8; ++e) v[e] = 32.f * b2f(kv8[e]);
      *(uint2*)&out8[gidx] = pack_fp8x8(v);
    } else if (MODE == 1) {
      const f32x8 b = *(const f32x8*)&bias[col0];
      float v[8], hv[8];
#pragma unroll
      for (int e = 0; e < 8; ++e) {
        const float c = b2f(kv8[e]);
        hv[e] = HW1_SCALE * c;
        v[e] = fast_tanh(c + b[e]);
      }
      *(uint2*)&out8b[gidx] = pack_fp8x8(hv);   // hW1 (fp8 x16)
      *(uint2*)&out8[gidx]  = pack_fp8x8(v);    // x1 (fp8)
    } else {  // MODE 5
      const f32x8 b = *(const f32x8*)&bias[col0];
      const f32x8 h8 = *(const f32x8*)&h0f[gidx];
      f32x8 o;
#pragma unroll
      for (int e = 0; e < 8; ++e) o[e] = h8[e] + DT6 * b2f(kv8[e]) + b[e];
      *(f32x8*)&outf[gidx] = o;
    }
  }
}

// =================== MX-fp8 GEMM (modes 2,3,4), BK=128 ===================
// C[i][j] = sum_k A[i][k]*Bt[j][k]*2^-5 via mfma_scale (B stored x32).
// MODE 2: out8 = fp8(tanh(C + bias))                      (x2 stage buffer)
// MODE 3: g = C; gout = fp8(g);
//         out8 = fp8(tanh(hW1/16 + p1*(g + c31) + b + p2*wl))
// MODE 4: hn = hW1/16 + DT/6*(g0+2g1+2g2+C) + DT*c31; hW1w = fp8(16*hn);
//         out8 = fp8(tanh(hn + b + p2*wl)); XT (+)= x2a+2x2b+2x2c+Ag
template<int MODE>
__global__ void __launch_bounds__(256, 2)
gemm_fp8(const u8* __restrict__ Ag, const u8* __restrict__ Bg,
         const float* __restrict__ bias, const float* __restrict__ wl,
         const float* __restrict__ c31,
         const u8* __restrict__ hW1r,
         const u8* __restrict__ g0p, const u8* __restrict__ g1p, const u8* __restrict__ g2p,
         const u8* __restrict__ x2a, const u8* __restrict__ x2b, const u8* __restrict__ x2c,
         u8* __restrict__ out8, u8* __restrict__ gout,
         ushort_t* __restrict__ bfio, u8* __restrict__ hW1w,
         float p1, float p2, int flag)
{
  constexpr int NT = 8;   // BK = 128 fp8 bytes
  constexpr float DT = 0.1f, DT6 = DT / 6.f;
  // per buffer: A 128x128B = 16KB | B 16KB; 2 buffers = 64KB. C-staging overlaid.
  __shared__ __align__(16) u8 bufs[2][32768];

  const int bid = blockIdx.x;
  const int nb = (int)gridDim.x >> 3;
  const int logical = (bid & 7) * nb + (bid >> 3);
  const int bm0 = (logical >> 3) * 128;
  const int bn0 = (logical & 7) * 128;

  const int tid = threadIdx.x;
  const int w = tid >> 6, l = tid & 63;
  const int wr = w >> 1, wc = w & 1;
  const int l31 = l & 31, kg = l >> 5;

  // ---- staging: slot s in [0,1024) holds (row = s>>3, phys chunk = s&7);
  //      source chunk clog = phys ^ (row&7); LDS dest linear slot*16 ----
  int so[4], ldo[4];
#pragma unroll
  for (int i = 0; i < 4; ++i) {
    const int slot = tid + i * 256;
    const int row = slot >> 3, phys = slot & 7;
    so[i] = row * 1024 + ((phys ^ (row & 7)) << 4);
    ldo[i] = slot << 4;
  }
  const u8* gA = Ag + (size_t)bm0 * 1024;
  const u8* gB = Bg + (size_t)bn0 * 1024;

#define STAGEF(s, t1) do { \
    GLOAD16(gA + so[0] + (t1) * 128, &bufs[s][ldo[0]]); \
    GLOAD16(gA + so[1] + (t1) * 128, &bufs[s][ldo[1]]); \
    GLOAD16(gA + so[2] + (t1) * 128, &bufs[s][ldo[2]]); \
    GLOAD16(gA + so[3] + (t1) * 128, &bufs[s][ldo[3]]); \
    GLOAD16(gB + so[0] + (t1) * 128, &bufs[s][16384 + ldo[0]]); \
    GLOAD16(gB + so[1] + (t1) * 128, &bufs[s][16384 + ldo[1]]); \
    GLOAD16(gB + so[2] + (t1) * 128, &bufs[s][16384 + ldo[2]]); \
    GLOAD16(gB + so[3] + (t1) * 128, &bufs[s][16384 + ldo[3]]); } while (0)

  // ---- fragment addresses: elem(row, chunk c) at row*128 + (c^(row&7))*16 ----
  auto ldsAddr = [](int row, int c) -> int {
    return row * 128 + ((c ^ (row & 7)) << 4);
  };
  const int ra0 = wr * 64 + l31, ra1 = ra0 + 32;
  const int rb0 = wc * 64 + l31, rb1 = rb0 + 32;
  const int ck0 = kg * 2, ck1 = 4 + kg * 2;   // chunk base for kblock 0 / 1
  const int a00 = ldsAddr(ra0, ck0), a00b = ldsAddr(ra0, ck0 + 1);
  const int a10 = ldsAddr(ra1, ck0), a10b = ldsAddr(ra1, ck0 + 1);
  const int b00 = 16384 + ldsAddr(rb0, ck0), b00b = 16384 + ldsAddr(rb0, ck0 + 1);
  const int b10 = 16384 + ldsAddr(rb1, ck0), b10b = 16384 + ldsAddr(rb1, ck0 + 1);
  const int a01 = ldsAddr(ra0, ck1), a01b = ldsAddr(ra0, ck1 + 1);
  const int a11 = ldsAddr(ra1, ck1), a11b = ldsAddr(ra1, ck1 + 1);
  const int b01 = 16384 + ldsAddr(rb0, ck1), b01b = 16384 + ldsAddr(rb0, ck1 + 1);
  const int b11 = 16384 + ldsAddr(rb1, ck1), b11b = 16384 + ldsAddr(rb1, ck1 + 1);

  f32x16 acc00, acc01, acc10, acc11;
#pragma unroll
  for (int i = 0; i < 16; ++i) { acc00[i] = 0.f; acc01[i] = 0.f; acc10[i] = 0.f; acc11[i] = 0.f; }

#define LD8(dst, o0, o1) do { \
    i32x4 lo_ = *(const i32x4*)(Lb + (o0)); \
    i32x4 hi_ = *(const i32x4*)(Lb + (o1)); \
    dst = (i32x8){lo_[0], lo_[1], lo_[2], lo_[3], hi_[0], hi_[1], hi_[2], hi_[3]}; } while (0)

  STAGEF(0, 0);

  for (int t = 0; t < NT; ++t) {
    const int cur = t & 1;
    __builtin_amdgcn_s_barrier();
    if (t + 1 < NT) {
      STAGEF(cur ^ 1, t + 1);
      asm volatile("s_waitcnt vmcnt(8)" ::: "memory");
    } else {
      asm volatile("s_waitcnt vmcnt(0)" ::: "memory");
    }
    __builtin_amdgcn_s_barrier();
    __builtin_amdgcn_sched_barrier(0);

    const u8* Lb = &bufs[cur][0];
    i32x8 a0, a1, b0, b1;
    // kblock 0
    LD8(a0, a00, a00b);
    LD8(a1, a10, a10b);
    LD8(b0, b00, b00b);
    LD8(b1, b10, b10b);
    __builtin_amdgcn_s_setprio(1);
    acc00 = __builtin_amdgcn_mfma_scale_f32_32x32x64_f8f6f4(a0, b0, acc00, 0, 0, 0, SCALE_ONE, 0, SCALE_INV32);
    acc01 = __builtin_amdgcn_mfma_scale_f32_32x32x64_f8f6f4(a0, b1, acc01, 0, 0, 0, SCALE_ONE, 0, SCALE_INV32);
    acc10 = __builtin_amdgcn_mfma_scale_f32_32x32x64_f8f6f4(a1, b0, acc10, 0, 0, 0, SCALE_ONE, 0, SCALE_INV32);
    acc11 = __builtin_amdgcn_mfma_scale_f32_32x32x64_f8f6f4(a1, b1, acc11, 0, 0, 0, SCALE_ONE, 0, SCALE_INV32);
    __builtin_amdgcn_s_setprio(0);
    // kblock 1
    LD8(a0, a01, a01b);
    LD8(a1, a11, a11b);
    LD8(b0, b01, b01b);
    LD8(b1, b11, b11b);
    __builtin_amdgcn_s_setprio(1);
    acc00 = __builtin_amdgcn_mfma_scale_f32_32x32x64_f8f6f4(a0, b0, acc00, 0, 0, 0, SCALE_ONE, 0, SCALE_INV32);
    acc01 = __builtin_amdgcn_mfma_scale_f32_32x32x64_f8f6f4(a0, b1, acc01, 0, 0, 0, SCALE_ONE, 0, SCALE_INV32);
    acc10 = __builtin_amdgcn_mfma_scale_f32_32x32x64_f8f6f4(a1, b0, acc10, 0, 0, 0, SCALE_ONE, 0, SCALE_INV32);
    acc11 = __builtin_amdgcn_mfma_scale_f32_32x32x64_f8f6f4(a1, b1, acc11, 0, 0, 0, SCALE_ONE, 0, SCALE_INV32);
    __builtin_amdgcn_s_setprio(0);
  }
#undef STAGEF

  // ---- hoisted epilogue state reads: overlap Cst staging + early epilogue ----
  uint2 hw_pre[8];
  if (MODE == 3 || MODE == 4) {
#pragma unroll
    for (int i = 0; i < 8; ++i) {
      const int chunk = tid + i * 256;
      const size_t gidx = (size_t)(bm0 + (chunk >> 4)) * 1024 + bn0 + (chunk & 15) * 8;
      hw_pre[i] = *(const uint2*)&hW1r[gidx];
    }
  }
  uint2 g0_pre[8], g1_pre[8], g2_pre[8];
  if (MODE == 4) {
#pragma unroll
    for (int i = 0; i < 8; ++i) {
      const int chunk = tid + i * 256;
      const size_t gidx = (size_t)(bm0 + (chunk >> 4)) * 1024 + bn0 + (chunk & 15) * 8;
      g0_pre[i] = *(const uint2*)&g0p[gidx];
      g1_pre[i] = *(const uint2*)&g1p[gidx];
      g2_pre[i] = *(const uint2*)&g2p[gidx];
    }
  }

  // ---- stage raw bf16(C) to LDS (overlaid on staging bufs — barrier first);
  //      32x32 C/D layout: col = lane&31, row = (reg&3)+8*(reg>>2)+4*(lane>>5)
  __syncthreads();
  ushort_t* Cst = (ushort_t*)&bufs[0][0];     // 128 x 136 bf16 = 34KB < 64KB
#define STORE_ACC(A_, mm, nn) do { \
    _Pragma("unroll") \
    for (int reg = 0; reg < 16; ++reg) { \
      const int lrow = wr * 64 + (mm) * 32 + (reg & 3) + 8 * (reg >> 2) + 4 * kg; \
      const int lcol = wc * 64 + (nn) * 32 + l31; \
      Cst[lrow * 136 + lcol] = f2bf(A_[reg]); } } while (0)
  STORE_ACC(acc00, 0, 0);
  STORE_ACC(acc01, 0, 1);
  STORE_ACC(acc10, 1, 0);
  STORE_ACC(acc11, 1, 1);
#undef STORE_ACC
  __syncthreads();

#pragma unroll
  for (int i = 0; i < 8; ++i) {
    const int chunk = tid + i * 256;
    const int row = chunk >> 4;
    const int cc = chunk & 15;
    const int col0 = bn0 + cc * 8;
    const us8 kv8 = *(const us8*)&Cst[row * 136 + cc * 8];
    const size_t gidx = (size_t)(bm0 + row) * 1024 + col0;

    if (MODE == 2) {
      const f32x8 b = *(const f32x8*)&bias[col0];
      float x2v[8];
#pragma unroll
      for (int e = 0; e < 8; ++e) x2v[e] = fast_tanh(b2f(kv8[e]) + b[e]);
      *(uint2*)&out8[gidx] = pack_fp8x8(x2v);
    } else if (MODE == 3) {
      const f32x8 b  = *(const f32x8*)&bias[col0];
      const f32x8 wv = *(const f32x8*)&wl[col0];
      const f32x8 cv = *(const f32x8*)&c31[col0];
      float hwv[8];
      fp8x8_to_f32(hw_pre[i], hwv);
      float gv[8], x1v[8];
#pragma unroll
      for (int e = 0; e < 8; ++e) {
        gv[e] = b2f(kv8[e]);
        x1v[e] = fast_tanh(hwv[e] * HW1_INV + p1 * (gv[e] + cv[e]) + b[e] + p2 * wv[e]);
      }
      *(uint2*)&gout[gidx] = pack_fp8x8(gv);
      *(uint2*)&out8[gidx] = pack_fp8x8(x1v);
    } else {  // MODE 4
      const f32x8 b  = *(const f32x8*)&bias[col0];
      const f32x8 wv = *(const f32x8*)&wl[col0];
      const f32x8 cv = *(const f32x8*)&c31[col0];
      float hwv[8];
      fp8x8_to_f32(hw_pre[i], hwv);
      float g0v[8], g1v[8], g2v[8];
      fp8x8_to_f32(g0_pre[i], g0v);
      fp8x8_to_f32(g1_pre[i], g1v);
      fp8x8_to_f32(g2_pre[i], g2v);
      // XT fold: x2a + 2*x2b + 2*x2c + x2d(=Ag)
      float va[8], vb[8], vc[8], vd[8];
      fp8x8_to_f32(*(const uint2*)&x2a[gidx], va);
      fp8x8_to_f32(*(const uint2*)&x2b[gidx], vb);
      fp8x8_to_f32(*(const uint2*)&x2c[gidx], vc);
      fp8x8_to_f32(*(const uint2*)&Ag[gidx], vd);
      us8 xtn;
      if (flag) {
#pragma unroll
        for (int e = 0; e < 8; ++e)
          xtn[e] = f2bf(va[e] + 2.f * (vb[e] + vc[e]) + vd[e]);
      } else {
        const us8 xo = *(const us8*)&bfio[gidx];
#pragma unroll
        for (int e = 0; e < 8; ++e)
          xtn[e] = f2bf(b2f(xo[e]) + va[e] + 2.f * (vb[e] + vc[e]) + vd[e]);
      }
      *(us8*)&bfio[gidx] = xtn;
      // h-state update: hW1 += DT/6*(g0 + 2g1 + 2g2 + g4) + DT*c31
      float x1v[8], hn16[8];
#pragma unroll
      for (int e = 0; e < 8; ++e) {
        const float gs = g0v[e] + 2.f * (g1v[e] + g2v[e]) + b2f(kv8[e]);
        const float hn = hwv[e] * HW1_INV + DT6 * gs + DT * cv[e];
        hn16[e] = HW1_SCALE * hn;
        x1v[e] = fast_tanh(hn + b[e] + p2 * wv[e]);
      }
      *(uint2*)&hW1w[gidx] = pack_fp8x8(hn16);
      *(uint2*)&out8[gidx] = pack_fp8x8(x1v);
    }
  }
}

extern "C" void kernel_launch(void* const* d_in, const int* in_sizes, int n_in,
                              void* d_out, int out_size, void* d_ws, size_t ws_size,
                              hipStream_t stream) {
  (void)in_sizes; (void)n_in; (void)out_size; (void)ws_size;
  const float* h_in = (const float*)d_in[0];
  const float* W1   = (const float*)d_in[1];   // 1025 x 1024
  const float* b1   = (const float*)d_in[2];
  const float* W2   = (const float*)d_in[3];
  const float* b2   = (const float*)d_in[4];
  const float* W3   = (const float*)d_in[5];
  const float* b3   = (const float*)d_in[6];
  const float* W1last = W1 + (size_t)1024 * 1024;

  char* ws = (char*)d_ws;
  ushort_t* W1t   = (ushort_t*)(ws);                   // 2 MiB (reused for W3^T at end)
  u8*       W2t8  = (u8*)      (ws + (2ull << 20));    // 1 MiB fp8 x32
  u8*       Bt318 = (u8*)      (ws + (3ull << 20));    // 1 MiB fp8 x32
  float*    c31   = (float*)   (ws + (4ull << 20));    // 4 KiB
  u8*       hW18  = (u8*)      (ws + (8ull << 20));    // 8 MiB fp8 x16 hW1
  u8*       x1    = (u8*)      (ws + (24ull << 20));   // 8 MiB fp8
  u8*       x2s0  = (u8*)      (ws + (32ull << 20));   // 8 MiB fp8
  u8*       x2s1  = (u8*)      (ws + (40ull << 20));   // 8 MiB fp8
  u8*       x2s2  = (u8*)      (ws + (48ull << 20));   // 8 MiB fp8
  u8*       x2s3  = (u8*)      (ws + (56ull << 20));   // 8 MiB fp8
  ushort_t* XT    = (ushort_t*)(ws + (64ull << 20));   // 16 MiB bf16 (W3b transient)
  u8*       g0    = (u8*)d_out;                        // 8 MiB fp8 (d_out, dead until final)
  u8*       g1    = (u8*)d_out + (8ull << 20);         // 8 MiB fp8
  u8*       g2    = (u8*)d_out + (16ull << 20);        // 8 MiB fp8
  ushort_t* hb    = (ushort_t*)d_out;                  // bf16 h (dead after MODE1)
  float*    OUT   = (float*)d_out;

  const float dt = 0.1f;
  constexpr int GRID = 512, BLK = 256;
  dim3 tb(32, 8), tg(32, 32);

  // ---- precompute ----
  transpose_bf16<<<tg, tb, 0, stream>>>(W1, W1t);
  transpose_fp8 <<<tg, tb, 0, stream>>>(W2, W2t8);
  conv_bf16<<<1024, 256, 0, stream>>>(W3, XT);         // W3b transient in XT slot
  conv_bf16<<<8192, 256, 0, stream>>>(h_in, hb);
  c31_kernel<<<4, 256, 0, stream>>>(W1t, b3, c31);
  gemm_bf16<0><<<64, BLK, 0, stream>>>(W1t, XT, nullptr, nullptr, Bt318, nullptr, nullptr);
  gemm_bf16<1><<<GRID, BLK, 0, stream>>>(hb, W1t, b1, hW18, x1, nullptr, nullptr);

  for (int step = 0; step < 10; ++step) {
    const float t0 = step * dt;
    // stage 1
    gemm_fp8<2><<<GRID, BLK, 0, stream>>>(x1, W2t8, b2, nullptr, nullptr, nullptr,
                                          nullptr, nullptr, nullptr, nullptr, nullptr, nullptr,
                                          x2s0, nullptr, nullptr, nullptr, 0.f, 0.f, 0);
    gemm_fp8<3><<<GRID, BLK, 0, stream>>>(x2s0, Bt318, b1, W1last, c31, hW18,
                                          nullptr, nullptr, nullptr, nullptr, nullptr, nullptr,
                                          x1, g0, nullptr, nullptr, 0.5f * dt, t0 + 0.5f * dt, 0);
    // stage 2
    gemm_fp8<2><<<GRID, BLK, 0, stream>>>(x1, W2t8, b2, nullptr, nullptr, nullptr,
                                          nullptr, nullptr, nullptr, nullptr, nullptr, nullptr,
                                          x2s1, nullptr, nullptr, nullptr, 0.f, 0.f, 0);
    gemm_fp8<3><<<GRID, BLK, 0, stream>>>(x2s1, Bt318, b1, W1last, c31, hW18,
                                          nullptr, nullptr, nullptr, nullptr, nullptr, nullptr,
                                          x1, g1, nullptr, nullptr, 0.5f * dt, t0 + 0.5f * dt, 0);
    // stage 3
    gemm_fp8<2><<<GRID, BLK, 0, stream>>>(x1, W2t8, b2, nullptr, nullptr, nullptr,
                                          nullptr, nullptr, nullptr, nullptr, nullptr, nullptr,
                                          x2s2, nullptr, nullptr, nullptr, 0.f, 0.f, 0);
    gemm_fp8<3><<<GRID, BLK, 0, stream>>>(x2s2, Bt318, b1, W1last, c31, hW18,
                                          nullptr, nullptr, nullptr, nullptr, nullptr, nullptr,
                                          x1, g2, nullptr, nullptr, dt, t0 + dt, 0);
    // stage 4
    gemm_fp8<2><<<GRID, BLK, 0, stream>>>(x1, W2t8, b2, nullptr, nullptr, nullptr,
                                          nullptr, nullptr, nullptr, nullptr, nullptr, nullptr,
                                          x2s3, nullptr, nullptr, nullptr, 0.f, 0.f, 0);
    if (step < 9) {
      gemm_fp8<4><<<GRID, BLK, 0, stream>>>(x2s3, Bt318, b1, W1last, c31, hW18,
                                            g0, g1, g2, x2s0, x2s1, x2s2,
                                            x1, nullptr, XT, hW18,
                                            0.f, t0 + dt, (step == 0));
    }
  }
  // step-9 XT contribution (no MODE4 needed — hW1 no longer used)
  xtfold<<<4096, 256, 0, stream>>>(x2s0, x2s1, x2s2, x2s3, XT);

  // final: h = h0 + dt/6 * XT@W3 + b3
  transpose_bf16<<<tg, tb, 0, stream>>>(W3, W1t);
  gemm_bf16<5><<<GRID, BLK, 0, stream>>>(XT, W1t, b3, nullptr, nullptr, h_in, OUT);
}